// Round 8
// baseline (247.126 us; speedup 1.0000x reference)
//
#include <hip/hip_runtime.h>
#include <hip/hip_bf16.h>

#define N_NODES 100000
#define N_EDGES 1600000
#define IN_F 128
#define OUT_F 64

#define RPB 64                        // rows per bucket
#define NB  1563                      // ceil(100000/64)
#define C_CHUNKS 250                  // edge chunks (scatter/hist blocks)
#define CHUNK 6400                    // edges per chunk; 250*6400 = 1,600,000
#define M_CNT (NB * C_CHUNKS)         // 390,750 bucket-major counters
#define SCANA_BLOCKS ((M_CNT + 1023) / 1024)   // 382
#define SORT_LDS_CAP 2048             // bucket len ~Poisson(1024); cap w/ fallback

typedef __attribute__((ext_vector_type(8))) short short8;
typedef __attribute__((ext_vector_type(4))) float f32x4;

#define LDS_PITCH 136

__device__ __forceinline__ unsigned short f2bf(float x) {
    unsigned u = __float_as_uint(x);
    return (unsigned short)((u + 0x7FFFu + ((u >> 16) & 1u)) >> 16);  // RNE
}
__device__ __forceinline__ float bf2f_u(unsigned short b) {
    return __uint_as_float((unsigned)b << 16);
}

// ---------------------------------------------------------------------------
// K1: per-chunk bucket histogram -> cnt[b*C_CHUNKS + c]; block C_CHUNKS
// additionally computes wa1 = W@a1, wa2 = W@a2 (fused, saves a launch).
// ---------------------------------------------------------------------------
__global__ __launch_bounds__(1024) void k_hist(
    const int* __restrict__ ei, int* __restrict__ cnt,
    const float* __restrict__ W, const float* __restrict__ a1,
    const float* __restrict__ a2, float* __restrict__ wa1, float* __restrict__ wa2)
{
    __shared__ int hl[NB];
    const int c = blockIdx.x;
    if (c == C_CHUNKS) {                 // fused k_wa
        const int k = threadIdx.x;
        if (k < IN_F) {
            float s1 = 0.f, s2 = 0.f;
            #pragma unroll 8
            for (int f = 0; f < OUT_F; f++) {
                const float w = W[k * OUT_F + f];
                s1 += w * a1[f];
                s2 += w * a2[f];
            }
            wa1[k] = s1;
            wa2[k] = s2;
        }
        return;
    }
    for (int i = threadIdx.x; i < NB; i += 1024) hl[i] = 0;
    __syncthreads();
    const int e0 = c * CHUNK;
    for (int i = threadIdx.x; i < CHUNK; i += 1024)
        atomicAdd(&hl[ei[e0 + i] >> 6], 1);
    __syncthreads();
    for (int b = threadIdx.x; b < NB; b += 1024)
        cnt[b * C_CHUNKS + c] = hl[b];
}

// ---------------------------------------------------------------------------
// K2: Wh = h @ W via bf16 MFMA; f1/f2 fused in fp32. Wh stored bf16.
// ---------------------------------------------------------------------------
__global__ __launch_bounds__(256) void k_gemm(
    const float* __restrict__ h, const float* __restrict__ W,
    const float* __restrict__ wa1, const float* __restrict__ wa2,
    unsigned short* __restrict__ Whb, float* __restrict__ f1, float* __restrict__ f2)
{
    __shared__ unsigned short Wt[OUT_F * LDS_PITCH];
    __shared__ unsigned short Al[16 * LDS_PITCH];

    const int tid  = threadIdx.x;
    const int lane = tid & 63;
    const int wav  = tid >> 6;
    const int quad = lane >> 4;
    const int nl   = lane & 15;

    for (int i = tid; i < IN_F * OUT_F; i += 256) {
        const int k = i >> 6, f = i & 63;
        Wt[f * LDS_PITCH + k] = f2bf(W[i]);
    }
    __syncthreads();

    short8 bfrag[4];
    #pragma unroll
    for (int ch = 0; ch < 4; ch++)
        bfrag[ch] = *(const short8*)&Wt[(wav * 16 + nl) * LDS_PITCH + ch * 32 + quad * 8];

    const int srow = tid >> 4;
    const int sc   = tid & 15;
    float w1r[8], w2r[8];
    #pragma unroll
    for (int j = 0; j < 8; j++) { w1r[j] = wa1[sc * 8 + j]; w2r[j] = wa2[sc * 8 + j]; }

    const int ntiles = N_NODES / 16;
    for (int tile = blockIdx.x; tile < ntiles; tile += gridDim.x) {
        const int base = tile * 16;
        __syncthreads();

        const float4 v0 = *(const float4*)&h[(base + srow) * IN_F + sc * 8];
        const float4 v1 = *(const float4*)&h[(base + srow) * IN_F + sc * 8 + 4];
        float p1 = v0.x * w1r[0] + v0.y * w1r[1] + v0.z * w1r[2] + v0.w * w1r[3]
                 + v1.x * w1r[4] + v1.y * w1r[5] + v1.z * w1r[6] + v1.w * w1r[7];
        float p2 = v0.x * w2r[0] + v0.y * w2r[1] + v0.z * w2r[2] + v0.w * w2r[3]
                 + v1.x * w2r[4] + v1.y * w2r[5] + v1.z * w2r[6] + v1.w * w2r[7];
        #pragma unroll
        for (int m = 8; m >= 1; m >>= 1) {
            p1 += __shfl_xor(p1, m, 64);
            p2 += __shfl_xor(p2, m, 64);
        }
        if (sc == 0) { f1[base + srow] = p1; f2[base + srow] = p2; }

        uint4 packed;
        packed.x = (unsigned)f2bf(v0.x) | ((unsigned)f2bf(v0.y) << 16);
        packed.y = (unsigned)f2bf(v0.z) | ((unsigned)f2bf(v0.w) << 16);
        packed.z = (unsigned)f2bf(v1.x) | ((unsigned)f2bf(v1.y) << 16);
        packed.w = (unsigned)f2bf(v1.z) | ((unsigned)f2bf(v1.w) << 16);
        *(uint4*)&Al[srow * LDS_PITCH + sc * 8] = packed;

        __syncthreads();

        f32x4 acc = {0.f, 0.f, 0.f, 0.f};
        #pragma unroll
        for (int ch = 0; ch < 4; ch++) {
            const short8 afrag = *(const short8*)&Al[nl * LDS_PITCH + ch * 32 + quad * 8];
            acc = __builtin_amdgcn_mfma_f32_16x16x32_bf16(afrag, bfrag[ch], acc, 0, 0, 0);
        }

        const int col = wav * 16 + nl;
        #pragma unroll
        for (int r = 0; r < 4; r++)
            Whb[(base + quad * 4 + r) * OUT_F + col] = f2bf(acc[r]);
    }
}

// ---------------------------------------------------------------------------
// K3a: per-1024-chunk totals of cnt
// ---------------------------------------------------------------------------
__global__ __launch_bounds__(256) void k_scanA(const int* __restrict__ cnt,
                                               int* __restrict__ bsum)
{
    __shared__ int sd[256];
    const int t = threadIdx.x;
    const int i0 = blockIdx.x * 1024 + t * 4;
    int s = 0;
    #pragma unroll
    for (int k = 0; k < 4; k++) {
        const int i = i0 + k;
        s += (i < M_CNT) ? cnt[i] : 0;
    }
    sd[t] = s; __syncthreads();
    for (int off = 128; off >= 1; off >>= 1) {
        if (t < off) sd[t] += sd[t + off];
        __syncthreads();
    }
    if (t == 0) bsum[blockIdx.x] = sd[0];
}

// ---------------------------------------------------------------------------
// K3b: in-place exclusive scan of cnt (each block reduces its bsum prefix)
// ---------------------------------------------------------------------------
__global__ __launch_bounds__(256) void k_scanC(int* __restrict__ cnt,
                                               const int* __restrict__ bsum)
{
    __shared__ int red[256];
    __shared__ int ts[256];
    const int t = threadIdx.x;

    int pv = 0;
    for (int i = t; i < (int)blockIdx.x; i += 256) pv += bsum[i];
    red[t] = pv; __syncthreads();
    for (int off = 128; off >= 1; off >>= 1) {
        if (t < off) red[t] += red[t + off];
        __syncthreads();
    }
    const int bpref = red[0];

    const int i0 = blockIdx.x * 1024 + t * 4;
    int v[4]; int s = 0;
    #pragma unroll
    for (int k = 0; k < 4; k++) {
        const int i = i0 + k;
        v[k] = (i < M_CNT) ? cnt[i] : 0;
        s += v[k];
    }
    ts[t] = s; __syncthreads();
    for (int off = 1; off < 256; off <<= 1) {
        const int x = (t >= off) ? ts[t - off] : 0;
        __syncthreads();
        ts[t] += x;
        __syncthreads();
    }
    int excl = ts[t] - s + bpref;
    #pragma unroll
    for (int k = 0; k < 4; k++) {
        const int i = i0 + k;
        if (i < M_CNT) cnt[i] = excl;
        excl += v[k];
    }
}

// ---------------------------------------------------------------------------
// K4: binned scatter (LDS cursors only). pair = {(rlocal<<17)|col, eexp}
// ---------------------------------------------------------------------------
__global__ __launch_bounds__(1024) void k_scatter(
    const int* __restrict__ ei,
    const float* __restrict__ f1,
    const float* __restrict__ f2,
    const int* __restrict__ cnt,
    uint2* __restrict__ pairs)
{
    __shared__ int cur[NB];
    const int c = blockIdx.x;
    for (int b = threadIdx.x; b < NB; b += 1024)
        cur[b] = cnt[b * C_CHUNKS + c];
    __syncthreads();

    const int e0 = c * CHUNK;
    for (int i = threadIdx.x; i < CHUNK; i += 1024) {
        const int r  = ei[e0 + i];
        const int cl = ei[N_EDGES + e0 + i];
        float x = f1[r] + f2[cl];
        x = (x >= 0.f) ? x : 0.2f * x;
        const float ee = __expf(x);
        const int pos = atomicAdd(&cur[r >> 6], 1);
        pairs[pos] = make_uint2(((unsigned)(r & 63) << 17) | (unsigned)cl,
                                __float_as_uint(ee));
    }
}

// ---------------------------------------------------------------------------
// K5: per-bucket streaming row-sort: pairs -> pairs2 (row-grouped) + rowptr.
// LDS staging of the bucket (cap 2048, global fallback).
// ---------------------------------------------------------------------------
__global__ __launch_bounds__(256) void k_sort(
    const int* __restrict__ cnt,
    const uint2* __restrict__ pairs,
    uint2* __restrict__ pairs2,
    int* __restrict__ rowptr)
{
    __shared__ uint2 sp[SORT_LDS_CAP];
    __shared__ int cnt64[64];
    __shared__ int cur64[64];

    const int b   = blockIdx.x;
    const int tid = threadIdx.x;
    const int start = cnt[b * C_CHUNKS];
    const int end   = (b == NB - 1) ? N_EDGES : cnt[(b + 1) * C_CHUNKS];
    const int len   = end - start;

    if (tid < 64) cnt64[tid] = 0;
    __syncthreads();

    for (int i = tid; i < len; i += 256) {
        const uint2 p = pairs[start + i];
        if (i < SORT_LDS_CAP) sp[i] = p;
        atomicAdd(&cnt64[p.x >> 17], 1);
    }
    __syncthreads();

    if (tid < 64) {
        const int v = cnt64[tid];
        int s = v;
        #pragma unroll
        for (int off = 1; off < 64; off <<= 1) {
            const int x = __shfl_up(s, off, 64);
            if (tid >= off) s += x;
        }
        cur64[tid] = s - v;
        const int g = b * 64 + tid;
        if (g < N_NODES) rowptr[g] = start + s - v;
    }
    __syncthreads();

    for (int i = tid; i < len; i += 256) {
        const uint2 p = (i < SORT_LDS_CAP) ? sp[i] : pairs[start + i];
        const int pos = atomicAdd(&cur64[p.x >> 17], 1);
        pairs2[start + pos] = p;
    }
    if (b == 0 && tid == 0) rowptr[N_NODES] = N_EDGES;
}

// ---------------------------------------------------------------------------
// K6: wave-per-node aggregation. ROUND-7 REWRITE: clamped full-width
// 8-edge batches (no serial tail ladder) + 2-stage software pipeline
// (prefetch batch b+1's pairs during batch b's gather+FMA). Overhang
// edges load clamped index end-1 and are masked with ee=0.
// ---------------------------------------------------------------------------
__global__ __launch_bounds__(256) void k_agg(
    const int* __restrict__ rowptr,
    const uint2* __restrict__ pairs2,
    const unsigned short* __restrict__ Whb,
    float* __restrict__ out)
{
    const int wid  = (blockIdx.x * 256 + threadIdx.x) >> 6;
    const int lane = threadIdx.x & 63;
    if (wid >= N_NODES) return;

    const int start = rowptr[wid];
    const int end   = rowptr[wid + 1];
    const int deg   = end - start;

    if (deg <= 0) {                       // isolated node: h' = 0, elu(0)=0
        out[wid * OUT_F + lane] = 0.f;
        return;
    }

    const int nb = (deg + 7) >> 3;        // full-width clamped batches

    float acc = 0.f, s = 0.f;
    uint2 p[8];

    // prologue: load batch 0 (clamped)
    #pragma unroll
    for (int k = 0; k < 8; k++) {
        const int idx = start + k;
        p[k] = pairs2[(idx < end) ? idx : (end - 1)];
    }

    int j = start;
    for (int b = 1; b < nb; b++) {
        const int jn = start + b * 8;
        uint2 q[8];
        #pragma unroll
        for (int k = 0; k < 8; k++) {     // prefetch next batch (clamped)
            const int idx = jn + k;
            q[k] = pairs2[(idx < end) ? idx : (end - 1)];
        }
        float wh[8];
        #pragma unroll
        for (int k = 0; k < 8; k++)
            wh[k] = bf2f_u(Whb[(((int)(p[k].x & 0x1FFFFu)) << 6) + lane]);
        #pragma unroll
        for (int k = 0; k < 8; k++) {
            const float ee = (j + k < end) ? __uint_as_float(p[k].y) : 0.f;
            acc += ee * wh[k];
            s   += ee;
        }
        #pragma unroll
        for (int k = 0; k < 8; k++) p[k] = q[k];
        j = jn;
    }

    // epilogue batch (masked)
    {
        float wh[8];
        #pragma unroll
        for (int k = 0; k < 8; k++)
            wh[k] = bf2f_u(Whb[(((int)(p[k].x & 0x1FFFFu)) << 6) + lane]);
        #pragma unroll
        for (int k = 0; k < 8; k++) {
            const float ee = (j + k < end) ? __uint_as_float(p[k].y) : 0.f;
            acc += ee * wh[k];
            s   += ee;
        }
    }

    const float r = acc / (s + 1e-10f);
    out[wid * OUT_F + lane] = (r > 0.f) ? r : expm1f(r);
}

extern "C" void kernel_launch(void* const* d_in, const int* in_sizes, int n_in,
                              void* d_out, int out_size, void* d_ws, size_t ws_size,
                              hipStream_t stream) {
    const float* h  = (const float*)d_in[0];
    const float* W  = (const float*)d_in[1];
    const float* a1 = (const float*)d_in[2];
    const float* a2 = (const float*)d_in[3];
    const int* ei   = (const int*)d_in[4];
    float* out      = (float*)d_out;

    float* ws = (float*)d_ws;
    unsigned short* Whb = (unsigned short*)ws;        // 6.4M ushort = 3.2M f
    float* f1     = ws + 3200000;                     // 100,000
    float* f2     = f1 + N_NODES;                     // 100,000
    float* wa1    = f2 + N_NODES;                     // 128
    float* wa2    = wa1 + 128;                        // 128
    int*   cnt    = (int*)(wa2 + 128);                // 390,750
    int*   bsum   = cnt + M_CNT;                      // 384
    int*   rowptr = bsum + 384;                       // 100,002
    int*   pad    = rowptr + 100002;
    if ((size_t)(pad - (int*)ws) & 1) pad++;          // 8B align
    uint2* pairs  = (uint2*)pad;                      // 1.6M x 8B
    uint2* pairs2 = pairs + N_EDGES;                  // 1.6M x 8B

    k_hist   <<<C_CHUNKS + 1, 1024, 0, stream>>>(ei, cnt, W, a1, a2, wa1, wa2);
    k_scanA  <<<SCANA_BLOCKS, 256, 0, stream>>>(cnt, bsum);
    k_scanC  <<<SCANA_BLOCKS, 256, 0, stream>>>(cnt, bsum);
    k_gemm   <<<1250, 256, 0, stream>>>(h, W, wa1, wa2, Whb, f1, f2);
    k_scatter<<<C_CHUNKS, 1024, 0, stream>>>(ei, f1, f2, cnt, pairs);
    k_sort   <<<NB, 256, 0, stream>>>(cnt, pairs, pairs2, rowptr);
    k_agg    <<<(N_NODES * 64 + 255) / 256, 256, 0, stream>>>(rowptr, pairs2, Whb, out);
}

// Round 9
// 224.105 us; speedup vs baseline: 1.1027x; 1.1027x over previous
//
#include <hip/hip_runtime.h>
#include <hip/hip_bf16.h>

#define N_NODES 100000
#define N_EDGES 1600000
#define IN_F 128
#define OUT_F 64

#define RPB 64                        // rows per bucket
#define NB  1563                      // ceil(100000/64)
#define C_CHUNKS 250                  // edge chunks (scatter/hist blocks)
#define CHUNK 6400                    // edges per chunk; 250*6400 = 1,600,000
#define M_CNT (NB * C_CHUNKS)         // 390,750 bucket-major counters
#define SCANA_BLOCKS ((M_CNT + 1023) / 1024)   // 382
#define SORT_LDS_CAP 2048             // bucket len ~Poisson(1024); cap w/ fallback
#define NTILES (N_NODES / 16)         // 6250 gemm tiles

typedef __attribute__((ext_vector_type(8))) short short8;
typedef __attribute__((ext_vector_type(4))) float f32x4;

#define LDS_PITCH 136

__device__ __forceinline__ unsigned short f2bf(float x) {
    unsigned u = __float_as_uint(x);
    return (unsigned short)((u + 0x7FFFu + ((u >> 16) & 1u)) >> 16);  // RNE
}
__device__ __forceinline__ float bf2f_u(unsigned short b) {
    return __uint_as_float((unsigned)b << 16);
}

// ---------------------------------------------------------------------------
// K1: per-chunk bucket histogram -> cnt[b*C_CHUNKS + c]; block C_CHUNKS
// additionally computes wa1 = W@a1, wa2 = W@a2 (fused, saves a launch).
// ---------------------------------------------------------------------------
__global__ __launch_bounds__(1024) void k_hist(
    const int* __restrict__ ei, int* __restrict__ cnt,
    const float* __restrict__ W, const float* __restrict__ a1,
    const float* __restrict__ a2, float* __restrict__ wa1, float* __restrict__ wa2)
{
    __shared__ int hl[NB];
    const int c = blockIdx.x;
    if (c == C_CHUNKS) {                 // fused k_wa
        const int k = threadIdx.x;
        if (k < IN_F) {
            float s1 = 0.f, s2 = 0.f;
            #pragma unroll 8
            for (int f = 0; f < OUT_F; f++) {
                const float w = W[k * OUT_F + f];
                s1 += w * a1[f];
                s2 += w * a2[f];
            }
            wa1[k] = s1;
            wa2[k] = s2;
        }
        return;
    }
    for (int i = threadIdx.x; i < NB; i += 1024) hl[i] = 0;
    __syncthreads();
    const int e0 = c * CHUNK;
    for (int i = threadIdx.x; i < CHUNK; i += 1024)
        atomicAdd(&hl[ei[e0 + i] >> 6], 1);
    __syncthreads();
    for (int b = threadIdx.x; b < NB; b += 1024)
        cnt[b * C_CHUNKS + c] = hl[b];
}

// ---------------------------------------------------------------------------
// K2: Wh = h @ W via bf16 MFMA; f1/f2 fused in fp32. Wh stored bf16.
// ROUND-8 CHANGE: 4 tiles (64 rows) per barrier pair — amortizes the
// 2 __syncthreads over 4x the work (barrier/overhead-bound before:
// MfmaUtil <1%, 51.2MB read = 8us floor vs ~35us measured).
// ---------------------------------------------------------------------------
__global__ __launch_bounds__(256) void k_gemm(
    const float* __restrict__ h, const float* __restrict__ W,
    const float* __restrict__ wa1, const float* __restrict__ wa2,
    unsigned short* __restrict__ Whb, float* __restrict__ f1, float* __restrict__ f2)
{
    __shared__ unsigned short Wt[OUT_F * LDS_PITCH];
    __shared__ unsigned short Al[64 * LDS_PITCH];    // 4 subtiles x 16 rows

    const int tid  = threadIdx.x;
    const int lane = tid & 63;
    const int wav  = tid >> 6;
    const int quad = lane >> 4;
    const int nl   = lane & 15;

    for (int i = tid; i < IN_F * OUT_F; i += 256) {
        const int k = i >> 6, f = i & 63;
        Wt[f * LDS_PITCH + k] = f2bf(W[i]);
    }
    __syncthreads();

    short8 bfrag[4];
    #pragma unroll
    for (int ch = 0; ch < 4; ch++)
        bfrag[ch] = *(const short8*)&Wt[(wav * 16 + nl) * LDS_PITCH + ch * 32 + quad * 8];

    const int srow = tid >> 4;
    const int sc   = tid & 15;
    float w1r[8], w2r[8];
    #pragma unroll
    for (int j = 0; j < 8; j++) { w1r[j] = wa1[sc * 8 + j]; w2r[j] = wa2[sc * 8 + j]; }

    const int ngroups = (NTILES + 3) / 4;            // 1563
    for (int g = blockIdx.x; g < ngroups; g += gridDim.x) {
        __syncthreads();                             // Al safe to overwrite

        #pragma unroll
        for (int sub = 0; sub < 4; sub++) {
            const int tile = g * 4 + sub;
            if (tile < NTILES) {
                const int base = tile * 16;
                const float4 v0 = *(const float4*)&h[(base + srow) * IN_F + sc * 8];
                const float4 v1 = *(const float4*)&h[(base + srow) * IN_F + sc * 8 + 4];
                float p1 = v0.x * w1r[0] + v0.y * w1r[1] + v0.z * w1r[2] + v0.w * w1r[3]
                         + v1.x * w1r[4] + v1.y * w1r[5] + v1.z * w1r[6] + v1.w * w1r[7];
                float p2 = v0.x * w2r[0] + v0.y * w2r[1] + v0.z * w2r[2] + v0.w * w2r[3]
                         + v1.x * w2r[4] + v1.y * w2r[5] + v1.z * w2r[6] + v1.w * w2r[7];
                #pragma unroll
                for (int m = 8; m >= 1; m >>= 1) {
                    p1 += __shfl_xor(p1, m, 64);
                    p2 += __shfl_xor(p2, m, 64);
                }
                if (sc == 0) { f1[base + srow] = p1; f2[base + srow] = p2; }

                uint4 packed;
                packed.x = (unsigned)f2bf(v0.x) | ((unsigned)f2bf(v0.y) << 16);
                packed.y = (unsigned)f2bf(v0.z) | ((unsigned)f2bf(v0.w) << 16);
                packed.z = (unsigned)f2bf(v1.x) | ((unsigned)f2bf(v1.y) << 16);
                packed.w = (unsigned)f2bf(v1.z) | ((unsigned)f2bf(v1.w) << 16);
                *(uint4*)&Al[(sub * 16 + srow) * LDS_PITCH + sc * 8] = packed;
            }
        }

        __syncthreads();

        #pragma unroll
        for (int sub = 0; sub < 4; sub++) {
            const int tile = g * 4 + sub;
            if (tile < NTILES) {
                const int base = tile * 16;
                f32x4 acc = {0.f, 0.f, 0.f, 0.f};
                #pragma unroll
                for (int ch = 0; ch < 4; ch++) {
                    const short8 afrag = *(const short8*)
                        &Al[(sub * 16 + nl) * LDS_PITCH + ch * 32 + quad * 8];
                    acc = __builtin_amdgcn_mfma_f32_16x16x32_bf16(afrag, bfrag[ch], acc, 0, 0, 0);
                }
                const int col = wav * 16 + nl;
                #pragma unroll
                for (int r = 0; r < 4; r++)
                    Whb[(base + quad * 4 + r) * OUT_F + col] = f2bf(acc[r]);
            }
        }
    }
}

// ---------------------------------------------------------------------------
// K3a: per-1024-chunk totals of cnt
// ---------------------------------------------------------------------------
__global__ __launch_bounds__(256) void k_scanA(const int* __restrict__ cnt,
                                               int* __restrict__ bsum)
{
    __shared__ int sd[256];
    const int t = threadIdx.x;
    const int i0 = blockIdx.x * 1024 + t * 4;
    int s = 0;
    #pragma unroll
    for (int k = 0; k < 4; k++) {
        const int i = i0 + k;
        s += (i < M_CNT) ? cnt[i] : 0;
    }
    sd[t] = s; __syncthreads();
    for (int off = 128; off >= 1; off >>= 1) {
        if (t < off) sd[t] += sd[t + off];
        __syncthreads();
    }
    if (t == 0) bsum[blockIdx.x] = sd[0];
}

// ---------------------------------------------------------------------------
// K3b: in-place exclusive scan of cnt (each block reduces its bsum prefix)
// ---------------------------------------------------------------------------
__global__ __launch_bounds__(256) void k_scanC(int* __restrict__ cnt,
                                               const int* __restrict__ bsum)
{
    __shared__ int red[256];
    __shared__ int ts[256];
    const int t = threadIdx.x;

    int pv = 0;
    for (int i = t; i < (int)blockIdx.x; i += 256) pv += bsum[i];
    red[t] = pv; __syncthreads();
    for (int off = 128; off >= 1; off >>= 1) {
        if (t < off) red[t] += red[t + off];
        __syncthreads();
    }
    const int bpref = red[0];

    const int i0 = blockIdx.x * 1024 + t * 4;
    int v[4]; int s = 0;
    #pragma unroll
    for (int k = 0; k < 4; k++) {
        const int i = i0 + k;
        v[k] = (i < M_CNT) ? cnt[i] : 0;
        s += v[k];
    }
    ts[t] = s; __syncthreads();
    for (int off = 1; off < 256; off <<= 1) {
        const int x = (t >= off) ? ts[t - off] : 0;
        __syncthreads();
        ts[t] += x;
        __syncthreads();
    }
    int excl = ts[t] - s + bpref;
    #pragma unroll
    for (int k = 0; k < 4; k++) {
        const int i = i0 + k;
        if (i < M_CNT) cnt[i] = excl;
        excl += v[k];
    }
}

// ---------------------------------------------------------------------------
// K4: binned scatter (LDS cursors only). pair = {(rlocal<<17)|col, eexp}
// ---------------------------------------------------------------------------
__global__ __launch_bounds__(1024) void k_scatter(
    const int* __restrict__ ei,
    const float* __restrict__ f1,
    const float* __restrict__ f2,
    const int* __restrict__ cnt,
    uint2* __restrict__ pairs)
{
    __shared__ int cur[NB];
    const int c = blockIdx.x;
    for (int b = threadIdx.x; b < NB; b += 1024)
        cur[b] = cnt[b * C_CHUNKS + c];
    __syncthreads();

    const int e0 = c * CHUNK;
    for (int i = threadIdx.x; i < CHUNK; i += 1024) {
        const int r  = ei[e0 + i];
        const int cl = ei[N_EDGES + e0 + i];
        float x = f1[r] + f2[cl];
        x = (x >= 0.f) ? x : 0.2f * x;
        const float ee = __expf(x);
        const int pos = atomicAdd(&cur[r >> 6], 1);
        pairs[pos] = make_uint2(((unsigned)(r & 63) << 17) | (unsigned)cl,
                                __float_as_uint(ee));
    }
}

// ---------------------------------------------------------------------------
// K5: per-bucket streaming row-sort: pairs -> pairs2 (row-grouped) + rowptr.
// LDS staging of the bucket (cap 2048, global fallback).
// ---------------------------------------------------------------------------
__global__ __launch_bounds__(256) void k_sort(
    const int* __restrict__ cnt,
    const uint2* __restrict__ pairs,
    uint2* __restrict__ pairs2,
    int* __restrict__ rowptr)
{
    __shared__ uint2 sp[SORT_LDS_CAP];
    __shared__ int cnt64[64];
    __shared__ int cur64[64];

    const int b   = blockIdx.x;
    const int tid = threadIdx.x;
    const int start = cnt[b * C_CHUNKS];
    const int end   = (b == NB - 1) ? N_EDGES : cnt[(b + 1) * C_CHUNKS];
    const int len   = end - start;

    if (tid < 64) cnt64[tid] = 0;
    __syncthreads();

    for (int i = tid; i < len; i += 256) {
        const uint2 p = pairs[start + i];
        if (i < SORT_LDS_CAP) sp[i] = p;
        atomicAdd(&cnt64[p.x >> 17], 1);
    }
    __syncthreads();

    if (tid < 64) {
        const int v = cnt64[tid];
        int s = v;
        #pragma unroll
        for (int off = 1; off < 64; off <<= 1) {
            const int x = __shfl_up(s, off, 64);
            if (tid >= off) s += x;
        }
        cur64[tid] = s - v;
        const int g = b * 64 + tid;
        if (g < N_NODES) rowptr[g] = start + s - v;
    }
    __syncthreads();

    for (int i = tid; i < len; i += 256) {
        const uint2 p = (i < SORT_LDS_CAP) ? sp[i] : pairs[start + i];
        const int pos = atomicAdd(&cur64[p.x >> 17], 1);
        pairs2[start + pos] = p;
    }
    if (b == 0 && tid == 0) rowptr[N_NODES] = N_EDGES;
}

// ---------------------------------------------------------------------------
// K6: aggregation. ROUND-8 REWRITE: 2 nodes per wave with dual independent
// 4-edge pipelines in the main loop (doubles memory-level parallelism per
// wave, amortizes the rowptr prologue; adjacent nodes -> contiguous rowptr
// and pairs2). Exact trip counts — no clamping/masking (round-8 lesson).
// ---------------------------------------------------------------------------
__global__ __launch_bounds__(256) void k_agg(
    const int* __restrict__ rowptr,
    const uint2* __restrict__ pairs2,
    const unsigned short* __restrict__ Whb,
    float* __restrict__ out)
{
    const int w    = (blockIdx.x * 256 + threadIdx.x) >> 6;  // wave id
    const int lane = threadIdx.x & 63;
    const int n0   = w * 2;
    if (n0 >= N_NODES) return;
    const int n1   = n0 + 1;

    const int s0 = rowptr[n0];
    const int e0 = rowptr[n0 + 1];
    const int e1 = rowptr[n0 + 2];

    float acc0 = 0.f, ss0 = 0.f, acc1 = 0.f, ss1 = 0.f;
    int j0 = s0, j1 = e0;

    // dual 4-edge pipelines (independent chains -> 8 gathers in flight)
    while (j0 + 4 <= e0 && j1 + 4 <= e1) {
        uint2 p0[4], p1[4];
        #pragma unroll
        for (int k = 0; k < 4; k++) p0[k] = pairs2[j0 + k];
        #pragma unroll
        for (int k = 0; k < 4; k++) p1[k] = pairs2[j1 + k];
        float wh0[4], wh1[4];
        #pragma unroll
        for (int k = 0; k < 4; k++)
            wh0[k] = bf2f_u(Whb[(((int)(p0[k].x & 0x1FFFFu)) << 6) + lane]);
        #pragma unroll
        for (int k = 0; k < 4; k++)
            wh1[k] = bf2f_u(Whb[(((int)(p1[k].x & 0x1FFFFu)) << 6) + lane]);
        #pragma unroll
        for (int k = 0; k < 4; k++) {
            const float a = __uint_as_float(p0[k].y);
            const float bb = __uint_as_float(p1[k].y);
            acc0 += a * wh0[k];  ss0 += a;
            acc1 += bb * wh1[k]; ss1 += bb;
        }
        j0 += 4; j1 += 4;
    }

    // solo finish node 0
    for (; j0 + 4 <= e0; j0 += 4) {
        uint2 p[4];
        #pragma unroll
        for (int k = 0; k < 4; k++) p[k] = pairs2[j0 + k];
        float wh[4];
        #pragma unroll
        for (int k = 0; k < 4; k++)
            wh[k] = bf2f_u(Whb[(((int)(p[k].x & 0x1FFFFu)) << 6) + lane]);
        #pragma unroll
        for (int k = 0; k < 4; k++) {
            const float a = __uint_as_float(p[k].y);
            acc0 += a * wh[k]; ss0 += a;
        }
    }
    for (; j0 < e0; j0++) {
        const uint2 p = pairs2[j0];
        const float a = __uint_as_float(p.y);
        acc0 += a * bf2f_u(Whb[(((int)(p.x & 0x1FFFFu)) << 6) + lane]);
        ss0  += a;
    }

    // solo finish node 1
    for (; j1 + 4 <= e1; j1 += 4) {
        uint2 p[4];
        #pragma unroll
        for (int k = 0; k < 4; k++) p[k] = pairs2[j1 + k];
        float wh[4];
        #pragma unroll
        for (int k = 0; k < 4; k++)
            wh[k] = bf2f_u(Whb[(((int)(p[k].x & 0x1FFFFu)) << 6) + lane]);
        #pragma unroll
        for (int k = 0; k < 4; k++) {
            const float a = __uint_as_float(p[k].y);
            acc1 += a * wh[k]; ss1 += a;
        }
    }
    for (; j1 < e1; j1++) {
        const uint2 p = pairs2[j1];
        const float a = __uint_as_float(p.y);
        acc1 += a * bf2f_u(Whb[(((int)(p.x & 0x1FFFFu)) << 6) + lane]);
        ss1  += a;
    }

    float r0 = acc0 / (ss0 + 1e-10f);
    float r1 = acc1 / (ss1 + 1e-10f);
    out[n0 * OUT_F + lane] = (r0 > 0.f) ? r0 : expm1f(r0);
    out[n1 * OUT_F + lane] = (r1 > 0.f) ? r1 : expm1f(r1);
}

extern "C" void kernel_launch(void* const* d_in, const int* in_sizes, int n_in,
                              void* d_out, int out_size, void* d_ws, size_t ws_size,
                              hipStream_t stream) {
    const float* h  = (const float*)d_in[0];
    const float* W  = (const float*)d_in[1];
    const float* a1 = (const float*)d_in[2];
    const float* a2 = (const float*)d_in[3];
    const int* ei   = (const int*)d_in[4];
    float* out      = (float*)d_out;

    float* ws = (float*)d_ws;
    unsigned short* Whb = (unsigned short*)ws;        // 6.4M ushort = 3.2M f
    float* f1     = ws + 3200000;                     // 100,000
    float* f2     = f1 + N_NODES;                     // 100,000
    float* wa1    = f2 + N_NODES;                     // 128
    float* wa2    = wa1 + 128;                        // 128
    int*   cnt    = (int*)(wa2 + 128);                // 390,750
    int*   bsum   = cnt + M_CNT;                      // 384
    int*   rowptr = bsum + 384;                       // 100,002
    int*   pad    = rowptr + 100002;
    if ((size_t)(pad - (int*)ws) & 1) pad++;          // 8B align
    uint2* pairs  = (uint2*)pad;                      // 1.6M x 8B
    uint2* pairs2 = pairs + N_EDGES;                  // 1.6M x 8B

    k_hist   <<<C_CHUNKS + 1, 1024, 0, stream>>>(ei, cnt, W, a1, a2, wa1, wa2);
    k_scanA  <<<SCANA_BLOCKS, 256, 0, stream>>>(cnt, bsum);
    k_scanC  <<<SCANA_BLOCKS, 256, 0, stream>>>(cnt, bsum);
    k_gemm   <<<782, 256, 0, stream>>>(h, W, wa1, wa2, Whb, f1, f2);
    k_scatter<<<C_CHUNKS, 1024, 0, stream>>>(ei, f1, f2, cnt, pairs);
    k_sort   <<<NB, 256, 0, stream>>>(cnt, pairs, pairs2, rowptr);
    k_agg    <<<(N_NODES / 2 * 64 + 255) / 256, 256, 0, stream>>>(rowptr, pairs2, Whb, out);
}